// Round 1
// baseline (132.600 us; speedup 1.0000x reference)
//
#include <hip/hip_runtime.h>
#include <math.h>

#define IMG 512
#define QO  255   // pooled qconv output dim (511/2)

// ---------------------------------------------------------------------------
// Kernel 1: build the fixed 16x16 circuit matrix M (phase-folded).
// Columns of U evolved from identity through 3 layers of (Rot x4, CNOT x4).
// Mout[r*16+k] = U[r][k] * (-i)^popcount(k)   (folds the RX -i phases)
// ---------------------------------------------------------------------------
__global__ void build_M(const float* __restrict__ qw, float2* __restrict__ Mout) {
    __shared__ float2 A[16][16];   // A[col][row]
    int tid = threadIdx.x;         // 128 threads
    for (int e = tid; e < 256; e += 128) {
        int col = e >> 4, row = e & 15;
        A[col][row] = make_float2(col == row ? 1.f : 0.f, 0.f);
    }
    __syncthreads();

    int col = tid >> 3;   // 0..15
    int p   = tid & 7;    // 0..7

    for (int l = 0; l < 3; ++l) {
        // Rot gates, qubit w = 0..3
        for (int w = 0; w < 4; ++w) {
            float phi = qw[(l*4 + w)*3 + 0];
            float th  = qw[(l*4 + w)*3 + 1];
            float om  = qw[(l*4 + w)*3 + 2];
            float ch = cosf(0.5f*th), sh = sinf(0.5f*th);
            float al = 0.5f*(phi + om), be = 0.5f*(phi - om);
            float ca = cosf(al), sa = sinf(al);
            float cb = cosf(be), sb = sinf(be);
            // U00 = e^{-i a} c ; U01 = -e^{+i b} s ; U10 = e^{-i b} s ; U11 = e^{+i a} c
            float2 U00 = make_float2( ca*ch, -sa*ch);
            float2 U01 = make_float2(-cb*sh, -sb*sh);
            float2 U10 = make_float2( cb*sh, -sb*sh);
            float2 U11 = make_float2( ca*ch,  sa*ch);

            int bp = 3 - w, m = 1 << bp;
            int low = p & (m - 1);
            int k0  = ((p ^ low) << 1) | low;
            int k1  = k0 | m;
            float2 a0 = A[col][k0], a1 = A[col][k1];
            float2 n0 = make_float2(U00.x*a0.x - U00.y*a0.y + U01.x*a1.x - U01.y*a1.y,
                                    U00.x*a0.y + U00.y*a0.x + U01.x*a1.y + U01.y*a1.x);
            float2 n1 = make_float2(U10.x*a0.x - U10.y*a0.y + U11.x*a1.x - U11.y*a1.y,
                                    U10.x*a0.y + U10.y*a0.x + U11.x*a1.y + U11.y*a1.x);
            A[col][k0] = n0;
            A[col][k1] = n1;
            __syncthreads();
        }
        // CNOT ring, range r
        int r = l % 3 + 1;
        for (int w = 0; w < 4; ++w) {
            int cq = w, tq = (w + r) & 3;
            int bpc = 3 - cq, bpt = 3 - tq;
            if (p < 4) {
                int fr0 = -1, fr1 = -1;
                for (int b = 0; b < 4; ++b) {
                    if (b != bpc && b != bpt) { if (fr0 < 0) fr0 = b; else fr1 = b; }
                }
                int k  = (1 << bpc) | ((p & 1) << fr0) | (((p >> 1) & 1) << fr1);
                int k2 = k | (1 << bpt);
                float2 t = A[col][k]; A[col][k] = A[col][k2]; A[col][k2] = t;
            }
            __syncthreads();
        }
    }

    // write out, folding (-i)^popcount(k) into column k
    for (int e = tid; e < 256; e += 128) {
        int row = e >> 4, k = e & 15;
        float2 v = A[k][row];
        int pc = __popc(k) & 3;
        float2 o;
        if      (pc == 0) o = v;
        else if (pc == 1) o = make_float2( v.y, -v.x);   // * (-i)
        else if (pc == 2) o = make_float2(-v.x, -v.y);   // * (-1)
        else              o = make_float2(-v.y,  v.x);   // * (+i)
        Mout[e] = o;
    }
}

// ---------------------------------------------------------------------------
// Kernel 2: fused quantum-conv + (sigmoid o maxpool2).
// One thread per pooled output pixel (255x255). Computes 4 patch sims,
// maxpools raw ez (sigmoid is monotone), applies sigmoid once.
// out layout: [4][255][255]
// ---------------------------------------------------------------------------
__global__ __launch_bounds__(256) void qconv_pool(const float* __restrict__ img,
                                                  const float2* __restrict__ Mg,
                                                  float* __restrict__ out) {
    __shared__ float2 Ms[256];
    int tid = threadIdx.x;
    Ms[tid] = Mg[tid];
    __syncthreads();

    int gid = blockIdx.x * 256 + tid;
    if (gid >= QO * QO) return;
    int i = gid / QO, j = gid - i * QO;
    int r0 = 2 * i, c0col = 2 * j;

    float cs[3][3], sn[3][3];
    #pragma unroll
    for (int rr = 0; rr < 3; ++rr) {
        #pragma unroll
        for (int cc = 0; cc < 3; ++cc) {
            float v = img[(r0 + rr) * IMG + c0col + cc];
            __sincosf(0.5f * v, &sn[rr][cc], &cs[rr][cc]);
        }
    }

    float mx0 = -1e30f, mx1 = -1e30f, mx2 = -1e30f, mx3 = -1e30f;

    #pragma unroll
    for (int pr = 0; pr < 2; ++pr) {
        #pragma unroll
        for (int pc = 0; pc < 2; ++pc) {
            float c0 = cs[pr][pc],     s0 = sn[pr][pc];
            float c1 = cs[pr][pc+1],   s1 = sn[pr][pc+1];
            float c2 = cs[pr+1][pc],   s2 = sn[pr+1][pc];
            float c3 = cs[pr+1][pc+1], s3 = sn[pr+1][pc+1];
            float t01[4] = {c0*c1, c0*s1, s0*c1, s0*s1};
            float t23[4] = {c2*c3, c2*s3, s2*c3, s2*s3};
            float a[16];
            #pragma unroll
            for (int k = 0; k < 16; ++k) a[k] = t01[k >> 2] * t23[k & 3];

            float e0 = 0.f, e1 = 0.f, e2 = 0.f, e3 = 0.f;
            for (int rw = 0; rw < 16; ++rw) {
                float re = 0.f, im = 0.f;
                #pragma unroll
                for (int k = 0; k < 16; ++k) {
                    float2 m = Ms[rw * 16 + k];
                    re = fmaf(m.x, a[k], re);
                    im = fmaf(m.y, a[k], im);
                }
                float pp = re * re + im * im;
                e0 += (rw & 8) ? -pp : pp;
                e1 += (rw & 4) ? -pp : pp;
                e2 += (rw & 2) ? -pp : pp;
                e3 += (rw & 1) ? -pp : pp;
            }
            mx0 = fmaxf(mx0, e0);
            mx1 = fmaxf(mx1, e1);
            mx2 = fmaxf(mx2, e2);
            mx3 = fmaxf(mx3, e3);
        }
    }

    out[0 * QO * QO + gid] = 1.f / (1.f + __expf(-mx0));
    out[1 * QO * QO + gid] = 1.f / (1.f + __expf(-mx1));
    out[2 * QO * QO + gid] = 1.f / (1.f + __expf(-mx2));
    out[3 * QO * QO + gid] = 1.f / (1.f + __expf(-mx3));
}

// ---------------------------------------------------------------------------
// Kernel 3: conv2 (4->20, 5x5) + bias + relu + maxpool2. out: [20][125][125]
// One thread per pooled output; 6x6 register window per input channel.
// ---------------------------------------------------------------------------
__global__ __launch_bounds__(256) void conv2_pool(const float* __restrict__ in,
                                                  const float* __restrict__ w,
                                                  const float* __restrict__ b,
                                                  float* __restrict__ out) {
    __shared__ float W[2000];
    __shared__ float B[20];
    for (int e = threadIdx.x; e < 2000; e += 256) W[e] = w[e];
    if (threadIdx.x < 20) B[threadIdx.x] = b[threadIdx.x];
    __syncthreads();

    int gid = blockIdx.x * 256 + threadIdx.x;
    if (gid >= 20 * 125 * 125) return;
    int oc = gid / (125 * 125);
    int rem = gid - oc * 125 * 125;
    int i = rem / 125, j = rem - i * 125;

    float a00 = 0.f, a01 = 0.f, a10 = 0.f, a11 = 0.f;
    for (int ic = 0; ic < 4; ++ic) {
        const float* ip = in + ic * QO * QO + (2 * i) * QO + 2 * j;
        float win[6][6];
        #pragma unroll
        for (int y = 0; y < 6; ++y)
            #pragma unroll
            for (int x = 0; x < 6; ++x)
                win[y][x] = ip[y * QO + x];
        const float* wp = W + (oc * 4 + ic) * 25;
        #pragma unroll
        for (int ky = 0; ky < 5; ++ky) {
            #pragma unroll
            for (int kx = 0; kx < 5; ++kx) {
                float wv = wp[ky * 5 + kx];
                a00 = fmaf(win[ky][kx],     wv, a00);
                a01 = fmaf(win[ky][kx+1],   wv, a01);
                a10 = fmaf(win[ky+1][kx],   wv, a10);
                a11 = fmaf(win[ky+1][kx+1], wv, a11);
            }
        }
    }
    float m = fmaxf(fmaxf(a00, a01), fmaxf(a10, a11));
    out[gid] = fmaxf(m + B[oc], 0.f);
}

// ---------------------------------------------------------------------------
// Kernel 4: conv3 (20->40, 3x3) + bias + relu. out: [40][123][123]
// One thread computes 4 output channels at one spatial position.
// Weights packed float4 across the 4-oc group in LDS.
// ---------------------------------------------------------------------------
__global__ __launch_bounds__(256) void conv3_k(const float* __restrict__ in,
                                               const float* __restrict__ w,
                                               const float* __restrict__ b,
                                               float* __restrict__ out) {
    __shared__ float4 W4[1800];   // [og 0..9][ic*9+kk]
    for (int e = threadIdx.x; e < 1800; e += 256) {
        int og = e / 180, rr = e - og * 180;
        int base = (og * 4) * 180 + rr;
        W4[e] = make_float4(w[base], w[base + 180], w[base + 360], w[base + 540]);
    }
    __syncthreads();

    int gid = blockIdx.x * 256 + threadIdx.x;
    if (gid >= 10 * 123 * 123) return;
    int og = gid / (123 * 123);
    int rem = gid - og * (123 * 123);
    int y = rem / 123, x = rem - y * 123;
    int oc0 = og * 4;

    float acc0 = 0.f, acc1 = 0.f, acc2 = 0.f, acc3 = 0.f;
    for (int ic = 0; ic < 20; ++ic) {
        const float* ip = in + ic * 125 * 125 + y * 125 + x;
        float v[3][3];
        #pragma unroll
        for (int ky = 0; ky < 3; ++ky)
            #pragma unroll
            for (int kx = 0; kx < 3; ++kx)
                v[ky][kx] = ip[ky * 125 + kx];
        #pragma unroll
        for (int ky = 0; ky < 3; ++ky) {
            #pragma unroll
            for (int kx = 0; kx < 3; ++kx) {
                float4 wv = W4[og * 180 + ic * 9 + ky * 3 + kx];
                float iv = v[ky][kx];
                acc0 = fmaf(iv, wv.x, acc0);
                acc1 = fmaf(iv, wv.y, acc1);
                acc2 = fmaf(iv, wv.z, acc2);
                acc3 = fmaf(iv, wv.w, acc3);
            }
        }
    }
    int sp = y * 123 + x;
    out[(oc0 + 0) * 123 * 123 + sp] = fmaxf(acc0 + b[oc0 + 0], 0.f);
    out[(oc0 + 1) * 123 * 123 + sp] = fmaxf(acc1 + b[oc0 + 1], 0.f);
    out[(oc0 + 2) * 123 * 123 + sp] = fmaxf(acc2 + b[oc0 + 2], 0.f);
    out[(oc0 + 3) * 123 * 123 + sp] = fmaxf(acc3 + b[oc0 + 3], 0.f);
}

// ---------------------------------------------------------------------------
// Kernel 5: adaptive max 4x4 over [40][123][123] -> 640 floats (flat NCHW).
// One 64-thread block per output element.
// ---------------------------------------------------------------------------
__global__ void amax_k(const float* __restrict__ in, float* __restrict__ out) {
    int ob = blockIdx.x;              // oc*16 + bi*4 + bj
    int oc = ob >> 4, bi = (ob >> 2) & 3, bj = ob & 3;
    int y0 = (bi * 123) >> 2, y1 = ((bi + 1) * 123 + 3) >> 2;
    int x0 = (bj * 123) >> 2, x1 = ((bj + 1) * 123 + 3) >> 2;
    int ny = y1 - y0, nx = x1 - x0, tot = ny * nx;
    float m = -1e30f;
    for (int e = threadIdx.x; e < tot; e += 64) {
        int yy = e / nx, xx = e - yy * nx;
        m = fmaxf(m, in[oc * 123 * 123 + (y0 + yy) * 123 + x0 + xx]);
    }
    #pragma unroll
    for (int o = 32; o > 0; o >>= 1) m = fmaxf(m, __shfl_down(m, o, 64));
    if (threadIdx.x == 0) out[ob] = m;
}

// ---------------------------------------------------------------------------
// Kernel 6: fc1 (640->64) + relu + fc2 (64->10). One 64-thread block.
// ---------------------------------------------------------------------------
__global__ void fc_k(const float* __restrict__ h, const float* __restrict__ w1,
                     const float* __restrict__ b1, const float* __restrict__ w2,
                     const float* __restrict__ b2, float* __restrict__ out) {
    __shared__ float hh[640];
    __shared__ float h1[64];
    int t = threadIdx.x;   // 64
    for (int e = t; e < 640; e += 64) hh[e] = h[e];
    __syncthreads();
    float acc = b1[t];
    for (int n = 0; n < 640; ++n) acc = fmaf(hh[n], w1[t * 640 + n], acc);
    h1[t] = fmaxf(acc, 0.f);
    __syncthreads();
    if (t < 10) {
        float o = b2[t];
        for (int n = 0; n < 64; ++n) o = fmaf(h1[n], w2[t * 64 + n], o);
        out[t] = o;
    }
}

// ---------------------------------------------------------------------------
extern "C" void kernel_launch(void* const* d_in, const int* in_sizes, int n_in,
                              void* d_out, int out_size, void* d_ws, size_t ws_size,
                              hipStream_t stream) {
    const float* x   = (const float*)d_in[0];
    const float* qw  = (const float*)d_in[1];
    const float* c2w = (const float*)d_in[2];
    const float* c2b = (const float*)d_in[3];
    const float* c3w = (const float*)d_in[4];
    const float* c3b = (const float*)d_in[5];
    const float* f1w = (const float*)d_in[6];
    const float* f1b = (const float*)d_in[7];
    const float* f2w = (const float*)d_in[8];
    const float* f2b = (const float*)d_in[9];
    float* out = (float*)d_out;

    float*  wsf   = (float*)d_ws;
    float2* M     = (float2*)d_ws;                 // 256 float2 = 2 KB
    float*  qout  = wsf + 512;                     // 4*255*255
    float*  c2out = qout + 4 * 255 * 255;          // 20*125*125
    float*  c3out = c2out + 20 * 125 * 125;        // 40*123*123
    float*  am    = c3out + 40 * 123 * 123;        // 640

    build_M<<<1, 128, 0, stream>>>(qw, M);
    qconv_pool<<<(QO * QO + 255) / 256, 256, 0, stream>>>(x, M, qout);
    conv2_pool<<<(20 * 125 * 125 + 255) / 256, 256, 0, stream>>>(qout, c2w, c2b, c2out);
    conv3_k<<<(10 * 123 * 123 + 255) / 256, 256, 0, stream>>>(c2out, c3w, c3b, c3out);
    amax_k<<<640, 64, 0, stream>>>(c3out, am);
    fc_k<<<1, 64, 0, stream>>>(am, f1w, f1b, f2w, f2b, out);
}